// Round 9
// baseline (158.387 us; speedup 1.0000x reference)
//
#include <hip/hip_runtime.h>
#include <hip/hip_bf16.h>
#include <stdint.h>

// Problem: B=2, S=2048, D=512, H=8, DK=64
#define S_LEN 2048
#define D_MOD 512
#define N_H   8
#define D_K   64

typedef short v8s __attribute__((ext_vector_type(8)));
typedef short v4s __attribute__((ext_vector_type(4)));
typedef float v4f __attribute__((ext_vector_type(4)));

__device__ __forceinline__ short f2bf(float f) {        // RNE
  union { float f; unsigned u; } a; a.f = f;
  unsigned u = a.u;
  u += 0x7fffu + ((u >> 16) & 1u);
  return (short)(u >> 16);
}
__device__ __forceinline__ short f2bfh(float f) {       // round-half-up (p>=0)
  union { float f; unsigned u; } a; a.f = f;
  return (short)((a.u + 0x8000u) >> 16);
}

__device__ __forceinline__ v4f mfma16(v8s a, v8s b, v4f c) {
  return __builtin_amdgcn_mfma_f32_16x16x32_bf16(a, b, c, 0, 0, 0);
}
__device__ __forceinline__ v4f mfma16x16(v4s a, v4s b, v4f c) {
  return __builtin_amdgcn_mfma_f32_16x16x16bf16_1k(a, b, c, 0, 0, 0);
}

// ---------------------------------------------------------------------------
// proj (R7-proven): z<3 -> C = A @ Wq^T for A in {q,k,v}, fp32 in, inline bf16
// cvt, VGPR-prefetch pipelined. z==3 -> maskpack (bid<256) or Wo->bf16.
// ---------------------------------------------------------------------------
__global__ __launch_bounds__(256) void proj_kernel(
    const float* __restrict__ q, const float* __restrict__ k,
    const float* __restrict__ v, const float* __restrict__ Wq,
    const float* __restrict__ Wo, const int* __restrict__ mask,
    short* __restrict__ QP, short* __restrict__ KP, short* __restrict__ VT,
    short* __restrict__ Wob, unsigned long long* __restrict__ mp)
{
  const int z = blockIdx.z;
  const int tid = threadIdx.x;
  if (z == 3) {
    int bid = blockIdx.x * 8 + blockIdx.y;           // 0..511
    if (bid < 256) {                                  // maskpack
      int id = bid * 256 + tid;                       // 0..65535
      const int4* m4 = (const int4*)(mask + (size_t)id * 64);
      unsigned long long w = 0ull;
#pragma unroll
      for (int j = 0; j < 16; j++) {
        int4 mv = m4[j];
        w |= (unsigned long long)(mv.x != 0) << (j * 4 + 0);
        w |= (unsigned long long)(mv.y != 0) << (j * 4 + 1);
        w |= (unsigned long long)(mv.z != 0) << (j * 4 + 2);
        w |= (unsigned long long)(mv.w != 0) << (j * 4 + 3);
      }
      mp[id] = w;
    } else {                                          // Wo cvt
      unsigned off = (bid - 256) * 256 + tid;         // 0..65535
      float4 x = ((const float4*)Wo)[off];
      v4s p; p.x = f2bf(x.x); p.y = f2bf(x.y); p.z = f2bf(x.z); p.w = f2bf(x.w);
      ((v4s*)Wob)[off] = p;
    }
    return;
  }
  const float* __restrict__ A = (z == 0) ? q : ((z == 1) ? k : v);
  const int m0 = blockIdx.x * 64, n0 = blockIdx.y * 64;
  const int wave = tid >> 6, lane = tid & 63;
  const int quad = lane >> 4, l15 = lane & 15;
  const int wm = wave >> 1, wn = wave & 1;
  __shared__ short As[64][72];
  __shared__ short Bs[64][72];
  v4f acc[2][2];
#pragma unroll
  for (int i = 0; i < 2; i++)
#pragma unroll
    for (int j = 0; j < 2; j++) acc[i][j] = (v4f){0.f, 0.f, 0.f, 0.f};

  float4 a4[4], b4[4];
#pragma unroll
  for (int i = 0; i < 4; i++) {
    int fi = tid + i * 256, r = fi >> 4, c = (fi & 15) << 2;
    a4[i] = *(const float4*)&A[(m0 + r) * 512 + c];
    b4[i] = *(const float4*)&Wq[(n0 + r) * 512 + c];
  }

  for (int kk = 0; kk < 512; kk += 64) {
    __syncthreads();
#pragma unroll
    for (int i = 0; i < 4; i++) {
      int fi = tid + i * 256, r = fi >> 4, c = (fi & 15) << 2;
      v4s ap; ap.x = f2bf(a4[i].x); ap.y = f2bf(a4[i].y); ap.z = f2bf(a4[i].z); ap.w = f2bf(a4[i].w);
      *(v4s*)&As[r][c] = ap;
      v4s bp; bp.x = f2bf(b4[i].x); bp.y = f2bf(b4[i].y); bp.z = f2bf(b4[i].z); bp.w = f2bf(b4[i].w);
      *(v4s*)&Bs[r][c] = bp;
    }
    __syncthreads();
    if (kk + 64 < 512) {
#pragma unroll
      for (int i = 0; i < 4; i++) {
        int fi = tid + i * 256, r = fi >> 4, c = (fi & 15) << 2;
        a4[i] = *(const float4*)&A[(m0 + r) * 512 + kk + 64 + c];
        b4[i] = *(const float4*)&Wq[(n0 + r) * 512 + kk + 64 + c];
      }
    }
#pragma unroll
    for (int ms = 0; ms < 2; ms++)
#pragma unroll
      for (int ns = 0; ns < 2; ns++)
#pragma unroll
        for (int ks = 0; ks < 2; ks++) {
          union { v8s v; v4s h2[2]; } a, bb;
          a.h2[0]  = *(const v4s*)&As[wm * 32 + ms * 16 + l15][ks * 32 + quad * 8];
          a.h2[1]  = *(const v4s*)&As[wm * 32 + ms * 16 + l15][ks * 32 + quad * 8 + 4];
          bb.h2[0] = *(const v4s*)&Bs[wn * 32 + ns * 16 + l15][ks * 32 + quad * 8];
          bb.h2[1] = *(const v4s*)&Bs[wn * 32 + ns * 16 + l15][ks * 32 + quad * 8 + 4];
          acc[ms][ns] = mfma16(a.v, bb.v, acc[ms][ns]);
        }
  }
#pragma unroll
  for (int ms = 0; ms < 2; ms++)
#pragma unroll
    for (int ns = 0; ns < 2; ns++) {
      int mb = m0 + wm * 32 + ms * 16 + quad * 4;
      int n  = n0 + wn * 32 + ns * 16 + l15;
      int bI = mb >> 11, s = mb & 2047, hh = n >> 6, dk = n & 63;
      if (z == 2) {
        v4s pv;
        pv.x = f2bf(acc[ms][ns][0]); pv.y = f2bf(acc[ms][ns][1]);
        pv.z = f2bf(acc[ms][ns][2]); pv.w = f2bf(acc[ms][ns][3]);
        *(v4s*)&VT[((bI * N_H + hh) * D_K + dk) * S_LEN + s] = pv;
      } else {
        short* dst = (z == 0) ? QP : KP;
#pragma unroll
        for (int r = 0; r < 4; r++)
          dst[((bI * N_H + hh) * S_LEN + (s + r)) * D_K + dk] = f2bf(acc[ms][ns][r]);
      }
    }
}

// ---------------------------------------------------------------------------
// Flash attention v5: one block = one key-group. 256 thr = 4 waves x 16 q-rows
// sharing ONE K/V tile-pair (18.4KB LDS); block owns a key QUARTER (8 tiles).
// Transposed-score register-P (R7-proven math), fixed-shift softmax,
// ones-MFMA row sums. Partials (fp32 X + l) written to workspace; the
// cross-block combine is folded into outproj (fixed shift -> addable).
// Grid: (32*4, H, B) = 2048 blocks -> 5 blocks/CU (VGPR-capped), fine-grained
// 4-wave barriers.
// ---------------------------------------------------------------------------
__global__ __launch_bounds__(256, 5) void attn_kernel(
    const short* __restrict__ QP, const short* __restrict__ KP,
    const short* __restrict__ VT, const unsigned long long* __restrict__ MP,
    float* __restrict__ XF, float* __restrict__ LP)
{
  const int bx = blockIdx.x;                 // 0..127
  const int qt = bx & 31, qu = bx >> 5;      // q-tile, key-quarter
  const int h = blockIdx.y, b = blockIdx.z;
  const int tid = threadIdx.x;               // 0..255
  const int wave = tid >> 6, lane = tid & 63;
  const int quad = lane >> 4, l15 = lane & 15;
  const short* Qh = QP + ((b * N_H + h) * S_LEN) * D_K;
  const short* Kh = KP + ((b * N_H + h) * S_LEN) * D_K;
  const short* Vh = VT + ((b * N_H + h) * D_K) * S_LEN;

  __shared__ short Ks[64][72];
  __shared__ short Vs[64][72];

  const int qrow = qt * 64 + wave * 16;      // this wave's 16 q-rows
  const int srow = tid >> 2;                 // staging row 0..63
  const int sc   = (tid & 3) * 16;           // staging col (shorts)
  const int ck0  = qu * 512;                 // key-quarter base

  v8s aQ[2];
#pragma unroll
  for (int ks = 0; ks < 2; ks++)
    aQ[ks] = *(const v8s*)&Qh[(qrow + l15) * D_K + ks * 32 + quad * 8];

  const float C1 = 0.18033688011112042f;     // 0.125 * log2(e)
  const float C2 = -11.541560327111707f;     // -8 * log2(e)
  const v4s ONES4 = {16256, 16256, 16256, 16256};
  v4f accX[4], accL = (v4f){0.f, 0.f, 0.f, 0.f};
#pragma unroll
  for (int u = 0; u < 4; u++) accX[u] = (v4f){0.f, 0.f, 0.f, 0.f};

  // prefetch tile 0
  v8s kr[2], vr[2];
#pragma unroll
  for (int j = 0; j < 2; j++) {
    kr[j] = *(const v8s*)&Kh[(ck0 + srow) * D_K + sc + j * 8];
    vr[j] = *(const v8s*)&Vh[srow * S_LEN + ck0 + sc + j * 8];
  }
  unsigned long long mwc = MP[(qrow + l15) * 32 + qu * 8];
  unsigned long long mwn = 0ull;

  for (int kt = 0; kt < 8; kt++) {
    __syncthreads();                         // prior compute done reading LDS
#pragma unroll
    for (int j = 0; j < 2; j++) {
      *(v8s*)&Ks[srow][sc + j * 8] = kr[j];
      *(v8s*)&Vs[srow][sc + j * 8] = vr[j];
    }
    __syncthreads();                         // tile visible to the 4 waves

    if (kt + 1 < 8) {
      const int c1 = ck0 + (kt + 1) * 64;
#pragma unroll
      for (int j = 0; j < 2; j++) {
        kr[j] = *(const v8s*)&Kh[(c1 + srow) * D_K + sc + j * 8];
        vr[j] = *(const v8s*)&Vh[srow * S_LEN + c1 + sc + j * 8];
      }
      mwn = MP[(qrow + l15) * 32 + qu * 8 + kt + 1];
    }

    // S^T per 16-key tile (lane: q=l15, key=tp*16+quad*4+r); exp -> bf16 A-frag
    v4s pa[4];
#pragma unroll
    for (int tp = 0; tp < 4; tp++) {
      v8s bK0 = *(const v8s*)&Ks[tp * 16 + l15][quad * 8];
      v8s bK1 = *(const v8s*)&Ks[tp * 16 + l15][32 + quad * 8];
      v4f s = mfma16(bK0, aQ[0], (v4f){0.f, 0.f, 0.f, 0.f});
      s = mfma16(bK1, aQ[1], s);
      unsigned mb = (unsigned)(mwc >> (tp * 16 + quad * 4));
      v4s pk;
#pragma unroll
      for (int r = 0; r < 4; r++) {
        float se = ((mb >> r) & 1u) ? s[r] : 0.0f;   // masked: exp2(C2)=e^-8
        float p = __builtin_amdgcn_exp2f(fmaf(se, C1, C2));
        pk[r] = f2bfh(p);
      }
      pa[tp] = pk;
    }

    // X += P @ V (register P); L += P @ 1 (row sums on MFMA pipe)
#pragma unroll
    for (int u = 0; u < 4; u++) {
      const short* vb_ = &Vs[u * 16 + l15][quad * 4];
#pragma unroll
      for (int tp = 0; tp < 4; tp++) {
        v4s bV = *(const v4s*)&vb_[tp * 16];
        accX[u] = mfma16x16(pa[tp], bV, accX[u]);
      }
    }
#pragma unroll
    for (int tp = 0; tp < 4; tp++)
      accL = mfma16x16(pa[tp], ONES4, accL);

    mwc = mwn;
  }

  // write fp32 partials: lane holds X[q=quad*4+r][dk=u*16+l15], l[q=quad*4+r]
  float* xq = XF + (size_t)qu * 2097152u;    // per-quarter plane [B,S,D] fp32
#pragma unroll
  for (int u = 0; u < 4; u++)
#pragma unroll
    for (int r = 0; r < 4; r++) {
      int srw = qrow + quad * 4 + r;
      xq[(b * S_LEN + srw) * D_MOD + h * D_K + u * 16 + l15] = accX[u][r];
    }
  if (l15 == 0) {
#pragma unroll
    for (int r = 0; r < 4; r++) {
      int srw = qrow + quad * 4 + r;
      LP[((qu * 2 + b) * S_LEN + srw) * N_H + h] = accL[r];
    }
  }
}

// ---------------------------------------------------------------------------
// outproj: out = (sum_qu XF[qu] / l) @ Wo^T. Combines the 4 attention
// partials during A-staging (fp32 sum, * 1/l, cvt bf16). l-table built once
// per block into LDS. VGPR-prefetch pipelined.
// ---------------------------------------------------------------------------
__global__ __launch_bounds__(256) void outproj_kernel(
    const float* __restrict__ XF, const float* __restrict__ LP,
    const short* __restrict__ Wob, float* __restrict__ out)
{
  const int m0 = blockIdx.x * 64, n0 = blockIdx.y * 64;
  const int tid = threadIdx.x;
  const int wave = tid >> 6, lane = tid & 63;
  const int quad = lane >> 4, l15 = lane & 15;
  const int wm = wave >> 1, wn = wave & 1;
  __shared__ short As[64][72];
  __shared__ short Bs[64][72];
  __shared__ float Linv[64][8];

  // build 1/l for this block's 64 rows x 8 heads
#pragma unroll
  for (int i = 0; i < 2; i++) {
    int e = tid + i * 256;                   // 0..511
    int rr = e >> 3, hh = e & 7;
    int s = m0 + rr, bb = s >> 11, sl = s & 2047;
    float l = 0.f;
#pragma unroll
    for (int qu = 0; qu < 4; qu++)
      l += LP[((qu * 2 + bb) * S_LEN + sl) * N_H + hh];
    Linv[rr][hh] = 1.0f / l;
  }

  v4f acc[2][2];
#pragma unroll
  for (int i = 0; i < 2; i++)
#pragma unroll
    for (int j = 0; j < 2; j++) acc[i][j] = (v4f){0.f, 0.f, 0.f, 0.f};

  // prefetch kk=0: A = sum of 4 fp32 partial planes; B = bf16 Wo
  float af[2][8];
  v8s b8[2];
#pragma unroll
  for (int i = 0; i < 2; i++) {
    int fi = tid + i * 256, r = fi >> 3, c = (fi & 7) << 3;
    size_t base = (size_t)(m0 + r) * 512 + c;
    float4 s0 = *(const float4*)&XF[base];
    float4 s1 = *(const float4*)&XF[base + 4];
#pragma unroll
    for (int qu = 1; qu < 4; qu++) {
      const float* p = XF + (size_t)qu * 2097152u + base;
      float4 t0 = *(const float4*)p;
      float4 t1 = *(const float4*)(p + 4);
      s0.x += t0.x; s0.y += t0.y; s0.z += t0.z; s0.w += t0.w;
      s1.x += t1.x; s1.y += t1.y; s1.z += t1.z; s1.w += t1.w;
    }
    af[i][0] = s0.x; af[i][1] = s0.y; af[i][2] = s0.z; af[i][3] = s0.w;
    af[i][4] = s1.x; af[i][5] = s1.y; af[i][6] = s1.z; af[i][7] = s1.w;
    b8[i] = *(const v8s*)&Wob[(n0 + r) * 512 + c];
  }
  __syncthreads();   // Linv ready (also covers first staging barrier)

  for (int kk = 0; kk < 512; kk += 64) {
#pragma unroll
    for (int i = 0; i < 2; i++) {
      int fi = tid + i * 256, r = fi >> 3, c = (fi & 7) << 3;
      float inv = Linv[r][kk >> 6];          // head uniform per kk
      v8s ap;
#pragma unroll
      for (int j = 0; j < 8; j++) ap[j] = f2bf(af[i][j] * inv);
      *(v8s*)&As[r][c] = ap;
      *(v8s*)&Bs[r][c] = b8[i];
    }
    __syncthreads();
    if (kk + 64 < 512) {
#pragma unroll
      for (int i = 0; i < 2; i++) {
        int fi = tid + i * 256, r = fi >> 3, c = (fi & 7) << 3;
        size_t base = (size_t)(m0 + r) * 512 + kk + 64 + c;
        float4 s0 = *(const float4*)&XF[base];
        float4 s1 = *(const float4*)&XF[base + 4];
#pragma unroll
        for (int qu = 1; qu < 4; qu++) {
          const float* p = XF + (size_t)qu * 2097152u + base;
          float4 t0 = *(const float4*)p;
          float4 t1 = *(const float4*)(p + 4);
          s0.x += t0.x; s0.y += t0.y; s0.z += t0.z; s0.w += t0.w;
          s1.x += t1.x; s1.y += t1.y; s1.z += t1.z; s1.w += t1.w;
        }
        af[i][0] = s0.x; af[i][1] = s0.y; af[i][2] = s0.z; af[i][3] = s0.w;
        af[i][4] = s1.x; af[i][5] = s1.y; af[i][6] = s1.z; af[i][7] = s1.w;
        b8[i] = *(const v8s*)&Wob[(n0 + r) * 512 + kk + 64 + c];
      }
    }
#pragma unroll
    for (int ms = 0; ms < 2; ms++)
#pragma unroll
      for (int ns = 0; ns < 2; ns++)
#pragma unroll
        for (int ks = 0; ks < 2; ks++) {
          union { v8s v; v4s h2[2]; } a, bb;
          a.h2[0]  = *(const v4s*)&As[wm * 32 + ms * 16 + l15][ks * 32 + quad * 8];
          a.h2[1]  = *(const v4s*)&As[wm * 32 + ms * 16 + l15][ks * 32 + quad * 8 + 4];
          bb.h2[0] = *(const v4s*)&Bs[wn * 32 + ns * 16 + l15][ks * 32 + quad * 8];
          bb.h2[1] = *(const v4s*)&Bs[wn * 32 + ns * 16 + l15][ks * 32 + quad * 8 + 4];
          acc[ms][ns] = mfma16(a.v, bb.v, acc[ms][ns]);
        }
    __syncthreads();
  }
#pragma unroll
  for (int ms = 0; ms < 2; ms++)
#pragma unroll
    for (int ns = 0; ns < 2; ns++) {
      int n = n0 + wn * 32 + ns * 16 + l15;
#pragma unroll
      for (int r = 0; r < 4; r++) {
        int m = m0 + wm * 32 + ms * 16 + quad * 4 + r;
        out[m * 512 + n] = acc[ms][ns][r];
      }
    }
}

// ---------------------------------------------------------------------------
extern "C" void kernel_launch(void* const* d_in, const int* in_sizes, int n_in,
                              void* d_out, int out_size, void* d_ws, size_t ws_size,
                              hipStream_t stream) {
  const float* q  = (const float*)d_in[0];
  const float* k  = (const float*)d_in[1];
  const float* v  = (const float*)d_in[2];
  const int* mask = (const int*)d_in[3];
  const float* Wq = (const float*)d_in[4];
  const float* Wo = (const float*)d_in[5];
  float* out = (float*)d_out;
  char* ws = (char*)d_ws;
  // ws: 0:QP 4MB | 4:KP | 8:VT | 16:MP 0.5MB | 16.5:Wob 0.5MB |
  //     17:XF 32MB (4 planes x 8MB fp32) | 49:LP 0.5MB
  short* QP = (short*)(ws);
  short* KP = (short*)(ws + (4u << 20));
  short* VT = (short*)(ws + (8u << 20));
  unsigned long long* MP = (unsigned long long*)(ws + (16u << 20));
  short* Wob = (short*)(ws + (16u << 20) + (512u << 10));
  float* XF = (float*)(ws + (17u << 20));
  float* LP = (float*)(ws + (49u << 20));

  proj_kernel<<<dim3(64, 8, 4), 256, 0, stream>>>(q, k, v, Wq, Wo, mask,
                                                  QP, KP, VT, Wob, MP);
  attn_kernel<<<dim3(128, N_H, 2), 256, 0, stream>>>(QP, KP, VT, MP, XF, LP);
  outproj_kernel<<<dim3(64, 8, 1), 256, 0, stream>>>(XF, LP, Wob, out);
}

// Round 10
// 150.412 us; speedup vs baseline: 1.0530x; 1.0530x over previous
//
#include <hip/hip_runtime.h>
#include <hip/hip_bf16.h>
#include <stdint.h>

// Problem: B=2, S=2048, D=512, H=8, DK=64
#define S_LEN 2048
#define D_MOD 512
#define N_H   8
#define D_K   64

typedef short v8s __attribute__((ext_vector_type(8)));
typedef short v4s __attribute__((ext_vector_type(4)));
typedef float v4f __attribute__((ext_vector_type(4)));

__device__ __forceinline__ short f2bf(float f) {        // RNE
  union { float f; unsigned u; } a; a.f = f;
  unsigned u = a.u;
  u += 0x7fffu + ((u >> 16) & 1u);
  return (short)(u >> 16);
}
__device__ __forceinline__ short f2bfh(float f) {       // round-half-up (p>=0)
  union { float f; unsigned u; } a; a.f = f;
  return (short)((a.u + 0x8000u) >> 16);
}
__device__ __forceinline__ float bf2f(short s) {        // exact
  union { unsigned u; float f; } x;
  x.u = ((unsigned)(unsigned short)s) << 16;
  return x.f;
}

__device__ __forceinline__ v4f mfma16(v8s a, v8s b, v4f c) {
  return __builtin_amdgcn_mfma_f32_16x16x32_bf16(a, b, c, 0, 0, 0);
}
__device__ __forceinline__ v4f mfma16x16(v4s a, v4s b, v4f c) {
  return __builtin_amdgcn_mfma_f32_16x16x16bf16_1k(a, b, c, 0, 0, 0);
}

// ---------------------------------------------------------------------------
// proj (R7-proven): z<3 -> C = A @ Wq^T for A in {q,k,v}, fp32 in, inline bf16
// cvt, VGPR-prefetch pipelined. z==3 -> maskpack (bid<256) or Wo->bf16.
// ---------------------------------------------------------------------------
__global__ __launch_bounds__(256) void proj_kernel(
    const float* __restrict__ q, const float* __restrict__ k,
    const float* __restrict__ v, const float* __restrict__ Wq,
    const float* __restrict__ Wo, const int* __restrict__ mask,
    short* __restrict__ QP, short* __restrict__ KP, short* __restrict__ VT,
    short* __restrict__ Wob, unsigned long long* __restrict__ mp)
{
  const int z = blockIdx.z;
  const int tid = threadIdx.x;
  if (z == 3) {
    int bid = blockIdx.x * 8 + blockIdx.y;           // 0..511
    if (bid < 256) {                                  // maskpack
      int id = bid * 256 + tid;                       // 0..65535
      const int4* m4 = (const int4*)(mask + (size_t)id * 64);
      unsigned long long w = 0ull;
#pragma unroll
      for (int j = 0; j < 16; j++) {
        int4 mv = m4[j];
        w |= (unsigned long long)(mv.x != 0) << (j * 4 + 0);
        w |= (unsigned long long)(mv.y != 0) << (j * 4 + 1);
        w |= (unsigned long long)(mv.z != 0) << (j * 4 + 2);
        w |= (unsigned long long)(mv.w != 0) << (j * 4 + 3);
      }
      mp[id] = w;
    } else {                                          // Wo cvt
      unsigned off = (bid - 256) * 256 + tid;         // 0..65535
      float4 x = ((const float4*)Wo)[off];
      v4s p; p.x = f2bf(x.x); p.y = f2bf(x.y); p.z = f2bf(x.z); p.w = f2bf(x.w);
      ((v4s*)Wob)[off] = p;
    }
    return;
  }
  const float* __restrict__ A = (z == 0) ? q : ((z == 1) ? k : v);
  const int m0 = blockIdx.x * 64, n0 = blockIdx.y * 64;
  const int wave = tid >> 6, lane = tid & 63;
  const int quad = lane >> 4, l15 = lane & 15;
  const int wm = wave >> 1, wn = wave & 1;
  __shared__ short As[64][72];
  __shared__ short Bs[64][72];
  v4f acc[2][2];
#pragma unroll
  for (int i = 0; i < 2; i++)
#pragma unroll
    for (int j = 0; j < 2; j++) acc[i][j] = (v4f){0.f, 0.f, 0.f, 0.f};

  float4 a4[4], b4[4];
#pragma unroll
  for (int i = 0; i < 4; i++) {
    int fi = tid + i * 256, r = fi >> 4, c = (fi & 15) << 2;
    a4[i] = *(const float4*)&A[(m0 + r) * 512 + c];
    b4[i] = *(const float4*)&Wq[(n0 + r) * 512 + c];
  }

  for (int kk = 0; kk < 512; kk += 64) {
    __syncthreads();
#pragma unroll
    for (int i = 0; i < 4; i++) {
      int fi = tid + i * 256, r = fi >> 4, c = (fi & 15) << 2;
      v4s ap; ap.x = f2bf(a4[i].x); ap.y = f2bf(a4[i].y); ap.z = f2bf(a4[i].z); ap.w = f2bf(a4[i].w);
      *(v4s*)&As[r][c] = ap;
      v4s bp; bp.x = f2bf(b4[i].x); bp.y = f2bf(b4[i].y); bp.z = f2bf(b4[i].z); bp.w = f2bf(b4[i].w);
      *(v4s*)&Bs[r][c] = bp;
    }
    __syncthreads();
    if (kk + 64 < 512) {
#pragma unroll
      for (int i = 0; i < 4; i++) {
        int fi = tid + i * 256, r = fi >> 4, c = (fi & 15) << 2;
        a4[i] = *(const float4*)&A[(m0 + r) * 512 + kk + 64 + c];
        b4[i] = *(const float4*)&Wq[(n0 + r) * 512 + kk + 64 + c];
      }
    }
#pragma unroll
    for (int ms = 0; ms < 2; ms++)
#pragma unroll
      for (int ns = 0; ns < 2; ns++)
#pragma unroll
        for (int ks = 0; ks < 2; ks++) {
          union { v8s v; v4s h2[2]; } a, bb;
          a.h2[0]  = *(const v4s*)&As[wm * 32 + ms * 16 + l15][ks * 32 + quad * 8];
          a.h2[1]  = *(const v4s*)&As[wm * 32 + ms * 16 + l15][ks * 32 + quad * 8 + 4];
          bb.h2[0] = *(const v4s*)&Bs[wn * 32 + ns * 16 + l15][ks * 32 + quad * 8];
          bb.h2[1] = *(const v4s*)&Bs[wn * 32 + ns * 16 + l15][ks * 32 + quad * 8 + 4];
          acc[ms][ns] = mfma16(a.v, bb.v, acc[ms][ns]);
        }
  }
#pragma unroll
  for (int ms = 0; ms < 2; ms++)
#pragma unroll
    for (int ns = 0; ns < 2; ns++) {
      int mb = m0 + wm * 32 + ms * 16 + quad * 4;
      int n  = n0 + wn * 32 + ns * 16 + l15;
      int bI = mb >> 11, s = mb & 2047, hh = n >> 6, dk = n & 63;
      if (z == 2) {
        v4s pv;
        pv.x = f2bf(acc[ms][ns][0]); pv.y = f2bf(acc[ms][ns][1]);
        pv.z = f2bf(acc[ms][ns][2]); pv.w = f2bf(acc[ms][ns][3]);
        *(v4s*)&VT[((bI * N_H + hh) * D_K + dk) * S_LEN + s] = pv;
      } else {
        short* dst = (z == 0) ? QP : KP;
#pragma unroll
        for (int r = 0; r < 4; r++)
          dst[((bI * N_H + hh) * S_LEN + (s + r)) * D_K + dk] = f2bf(acc[ms][ns][r]);
      }
    }
}

// ---------------------------------------------------------------------------
// Flash attention v6: one block = one key-quarter (R9 structure), but
// partials stored as BF16 planes (half the traffic) and launch_bounds
// (256,4) => 128 VGPRs (no spill risk), 4 blocks/CU = 16 waves/CU.
// 256 thr = 4 waves x 16 q-rows sharing one K/V tile-pair (18.4KB LDS);
// block owns 8 key-tiles. Transposed-score register-P, fixed-shift softmax,
// ones-MFMA row sums. Combine folded into outproj (fixed shift -> addable).
// Grid: (32*4, H, B) = 2048 blocks.
// ---------------------------------------------------------------------------
__global__ __launch_bounds__(256, 4) void attn_kernel(
    const short* __restrict__ QP, const short* __restrict__ KP,
    const short* __restrict__ VT, const unsigned long long* __restrict__ MP,
    short* __restrict__ XB, float* __restrict__ LP)
{
  const int bx = blockIdx.x;                 // 0..127
  const int qt = bx & 31, qu = bx >> 5;      // q-tile, key-quarter
  const int h = blockIdx.y, b = blockIdx.z;
  const int tid = threadIdx.x;               // 0..255
  const int wave = tid >> 6, lane = tid & 63;
  const int quad = lane >> 4, l15 = lane & 15;
  const short* Qh = QP + ((b * N_H + h) * S_LEN) * D_K;
  const short* Kh = KP + ((b * N_H + h) * S_LEN) * D_K;
  const short* Vh = VT + ((b * N_H + h) * D_K) * S_LEN;

  __shared__ short Ks[64][72];
  __shared__ short Vs[64][72];

  const int qrow = qt * 64 + wave * 16;      // this wave's 16 q-rows
  const int srow = tid >> 2;                 // staging row 0..63
  const int sc   = (tid & 3) * 16;           // staging col (shorts)
  const int ck0  = qu * 512;                 // key-quarter base

  v8s aQ[2];
#pragma unroll
  for (int ks = 0; ks < 2; ks++)
    aQ[ks] = *(const v8s*)&Qh[(qrow + l15) * D_K + ks * 32 + quad * 8];

  const float C1 = 0.18033688011112042f;     // 0.125 * log2(e)
  const float C2 = -11.541560327111707f;     // -8 * log2(e)
  const v4s ONES4 = {16256, 16256, 16256, 16256};
  v4f accX[4], accL = (v4f){0.f, 0.f, 0.f, 0.f};
#pragma unroll
  for (int u = 0; u < 4; u++) accX[u] = (v4f){0.f, 0.f, 0.f, 0.f};

  // prefetch tile 0
  v8s kr[2], vr[2];
#pragma unroll
  for (int j = 0; j < 2; j++) {
    kr[j] = *(const v8s*)&Kh[(ck0 + srow) * D_K + sc + j * 8];
    vr[j] = *(const v8s*)&Vh[srow * S_LEN + ck0 + sc + j * 8];
  }
  unsigned long long mwc = MP[(qrow + l15) * 32 + qu * 8];
  unsigned long long mwn = 0ull;

  for (int kt = 0; kt < 8; kt++) {
    __syncthreads();                         // prior compute done reading LDS
#pragma unroll
    for (int j = 0; j < 2; j++) {
      *(v8s*)&Ks[srow][sc + j * 8] = kr[j];
      *(v8s*)&Vs[srow][sc + j * 8] = vr[j];
    }
    __syncthreads();                         // tile visible to the 4 waves

    if (kt + 1 < 8) {
      const int c1 = ck0 + (kt + 1) * 64;
#pragma unroll
      for (int j = 0; j < 2; j++) {
        kr[j] = *(const v8s*)&Kh[(c1 + srow) * D_K + sc + j * 8];
        vr[j] = *(const v8s*)&Vh[srow * S_LEN + c1 + sc + j * 8];
      }
      mwn = MP[(qrow + l15) * 32 + qu * 8 + kt + 1];
    }

    // S^T per 16-key tile (lane: q=l15, key=tp*16+quad*4+r); exp -> bf16 A-frag
    v4s pa[4];
#pragma unroll
    for (int tp = 0; tp < 4; tp++) {
      v8s bK0 = *(const v8s*)&Ks[tp * 16 + l15][quad * 8];
      v8s bK1 = *(const v8s*)&Ks[tp * 16 + l15][32 + quad * 8];
      v4f s = mfma16(bK0, aQ[0], (v4f){0.f, 0.f, 0.f, 0.f});
      s = mfma16(bK1, aQ[1], s);
      unsigned mb = (unsigned)(mwc >> (tp * 16 + quad * 4));
      v4s pk;
#pragma unroll
      for (int r = 0; r < 4; r++) {
        float se = ((mb >> r) & 1u) ? s[r] : 0.0f;   // masked: exp2(C2)=e^-8
        float p = __builtin_amdgcn_exp2f(fmaf(se, C1, C2));
        pk[r] = f2bfh(p);
      }
      pa[tp] = pk;
    }

    // X += P @ V (register P); L += P @ 1 (row sums on MFMA pipe)
#pragma unroll
    for (int u = 0; u < 4; u++) {
      const short* vb_ = &Vs[u * 16 + l15][quad * 4];
#pragma unroll
      for (int tp = 0; tp < 4; tp++) {
        v4s bV = *(const v4s*)&vb_[tp * 16];
        accX[u] = mfma16x16(pa[tp], bV, accX[u]);
      }
    }
#pragma unroll
    for (int tp = 0; tp < 4; tp++)
      accL = mfma16x16(pa[tp], ONES4, accL);

    mwc = mwn;
  }

  // write bf16 partials: lane holds X[q=quad*4+r][dk=u*16+l15], l[q=quad*4+r]
  short* xq = XB + (size_t)qu * 2097152u;    // per-quarter plane [B,S,D] bf16
#pragma unroll
  for (int u = 0; u < 4; u++)
#pragma unroll
    for (int r = 0; r < 4; r++) {
      int srw = qrow + quad * 4 + r;
      xq[(b * S_LEN + srw) * D_MOD + h * D_K + u * 16 + l15] = f2bf(accX[u][r]);
    }
  if (l15 == 0) {
#pragma unroll
    for (int r = 0; r < 4; r++) {
      int srw = qrow + quad * 4 + r;
      LP[((qu * 2 + b) * S_LEN + srw) * N_H + h] = accL[r];
    }
  }
}

// ---------------------------------------------------------------------------
// outproj: out = (sum_qu XB[qu] / l) @ Wo^T. Combines the 4 bf16 partial
// planes during A-staging (exact bf16->fp32 unpack, fp32 sum, * 1/l, repack).
// l-table in LDS. VGPR-prefetch pipelined.
// ---------------------------------------------------------------------------
__global__ __launch_bounds__(256) void outproj_kernel(
    const short* __restrict__ XB, const float* __restrict__ LP,
    const short* __restrict__ Wob, float* __restrict__ out)
{
  const int m0 = blockIdx.x * 64, n0 = blockIdx.y * 64;
  const int tid = threadIdx.x;
  const int wave = tid >> 6, lane = tid & 63;
  const int quad = lane >> 4, l15 = lane & 15;
  const int wm = wave >> 1, wn = wave & 1;
  __shared__ short As[64][72];
  __shared__ short Bs[64][72];
  __shared__ float Linv[64][8];

  // build 1/l for this block's 64 rows x 8 heads
#pragma unroll
  for (int i = 0; i < 2; i++) {
    int e = tid + i * 256;                   // 0..511
    int rr = e >> 3, hh = e & 7;
    int s = m0 + rr, bb = s >> 11, sl = s & 2047;
    float l = 0.f;
#pragma unroll
    for (int qu = 0; qu < 4; qu++)
      l += LP[((qu * 2 + bb) * S_LEN + sl) * N_H + hh];
    Linv[rr][hh] = 1.0f / l;
  }

  v4f acc[2][2];
#pragma unroll
  for (int i = 0; i < 2; i++)
#pragma unroll
    for (int j = 0; j < 2; j++) acc[i][j] = (v4f){0.f, 0.f, 0.f, 0.f};

  // prefetch kk=0: A = sum of 4 bf16 partial planes; B = bf16 Wo
  float af[2][8];
  v8s b8[2];
#pragma unroll
  for (int i = 0; i < 2; i++) {
    int fi = tid + i * 256, r = fi >> 3, c = (fi & 7) << 3;
    size_t base = (size_t)(m0 + r) * 512 + c;
#pragma unroll
    for (int j = 0; j < 8; j++) af[i][j] = 0.f;
#pragma unroll
    for (int qu = 0; qu < 4; qu++) {
      v8s t = *(const v8s*)(XB + (size_t)qu * 2097152u + base);
#pragma unroll
      for (int j = 0; j < 8; j++) af[i][j] += bf2f(t[j]);
    }
    b8[i] = *(const v8s*)&Wob[(n0 + r) * 512 + c];
  }
  __syncthreads();   // Linv ready

  for (int kk = 0; kk < 512; kk += 64) {
#pragma unroll
    for (int i = 0; i < 2; i++) {
      int fi = tid + i * 256, r = fi >> 3, c = (fi & 7) << 3;
      float inv = Linv[r][kk >> 6];          // head uniform per kk
      v8s ap;
#pragma unroll
      for (int j = 0; j < 8; j++) ap[j] = f2bf(af[i][j] * inv);
      *(v8s*)&As[r][c] = ap;
      *(v8s*)&Bs[r][c] = b8[i];
    }
    __syncthreads();
    if (kk + 64 < 512) {
#pragma unroll
      for (int i = 0; i < 2; i++) {
        int fi = tid + i * 256, r = fi >> 3, c = (fi & 7) << 3;
        size_t base = (size_t)(m0 + r) * 512 + kk + 64 + c;
#pragma unroll
        for (int j = 0; j < 8; j++) af[i][j] = 0.f;
#pragma unroll
        for (int qu = 0; qu < 4; qu++) {
          v8s t = *(const v8s*)(XB + (size_t)qu * 2097152u + base);
#pragma unroll
          for (int j = 0; j < 8; j++) af[i][j] += bf2f(t[j]);
        }
        b8[i] = *(const v8s*)&Wob[(n0 + r) * 512 + kk + 64 + c];
      }
    }
#pragma unroll
    for (int ms = 0; ms < 2; ms++)
#pragma unroll
      for (int ns = 0; ns < 2; ns++)
#pragma unroll
        for (int ks = 0; ks < 2; ks++) {
          union { v8s v; v4s h2[2]; } a, bb;
          a.h2[0]  = *(const v4s*)&As[wm * 32 + ms * 16 + l15][ks * 32 + quad * 8];
          a.h2[1]  = *(const v4s*)&As[wm * 32 + ms * 16 + l15][ks * 32 + quad * 8 + 4];
          bb.h2[0] = *(const v4s*)&Bs[wn * 32 + ns * 16 + l15][ks * 32 + quad * 8];
          bb.h2[1] = *(const v4s*)&Bs[wn * 32 + ns * 16 + l15][ks * 32 + quad * 8 + 4];
          acc[ms][ns] = mfma16(a.v, bb.v, acc[ms][ns]);
        }
    __syncthreads();
  }
#pragma unroll
  for (int ms = 0; ms < 2; ms++)
#pragma unroll
    for (int ns = 0; ns < 2; ns++) {
      int n = n0 + wn * 32 + ns * 16 + l15;
#pragma unroll
      for (int r = 0; r < 4; r++) {
        int m = m0 + wm * 32 + ms * 16 + quad * 4 + r;
        out[m * 512 + n] = acc[ms][ns][r];
      }
    }
}

// ---------------------------------------------------------------------------
extern "C" void kernel_launch(void* const* d_in, const int* in_sizes, int n_in,
                              void* d_out, int out_size, void* d_ws, size_t ws_size,
                              hipStream_t stream) {
  const float* q  = (const float*)d_in[0];
  const float* k  = (const float*)d_in[1];
  const float* v  = (const float*)d_in[2];
  const int* mask = (const int*)d_in[3];
  const float* Wq = (const float*)d_in[4];
  const float* Wo = (const float*)d_in[5];
  float* out = (float*)d_out;
  char* ws = (char*)d_ws;
  // ws: 0:QP 4MB | 4:KP | 8:VT | 16:MP 0.5MB | 16.5:Wob 0.5MB |
  //     17:XB 16MB (4 planes x 4MB bf16) | 33:LP 0.5MB
  short* QP = (short*)(ws);
  short* KP = (short*)(ws + (4u << 20));
  short* VT = (short*)(ws + (8u << 20));
  unsigned long long* MP = (unsigned long long*)(ws + (16u << 20));
  short* Wob = (short*)(ws + (16u << 20) + (512u << 10));
  short* XB = (short*)(ws + (17u << 20));
  float* LP = (float*)(ws + (33u << 20));

  proj_kernel<<<dim3(64, 8, 4), 256, 0, stream>>>(q, k, v, Wq, Wo, mask,
                                                  QP, KP, VT, Wob, MP);
  attn_kernel<<<dim3(128, N_H, 2), 256, 0, stream>>>(QP, KP, VT, MP, XB, LP);
  outproj_kernel<<<dim3(64, 8, 1), 256, 0, stream>>>(XB, LP, Wob, out);
}